// Round 6
// baseline (397.060 us; speedup 1.0000x reference)
//
#include <hip/hip_runtime.h>
#include <cstdint>
#include <cstddef>

#define BETA 5.5f
#define ALPHA 0.5f

constexpr int D   = 512;     // feature dim
constexpr int NB  = 4096;    // queries
constexpr int NK  = 16384;   // keys
constexpr int BQ  = 64;      // query tile per block
constexpr int BN  = 64;      // key chunk
constexpr int NSPLIT = 8;    // one nsplit per XCD -> KnF+KnT slice = 4MB = L2
constexpr int NRANGE = NK / NSPLIT;   // 2048
constexpr int CHUNKS = NRANGE / BN;   // 32
constexpr int KROW = D + 8;           // padded LDS row in norm_k (bf16 elems)
constexpr int PROW = BN + 8;          // padded P row: 72
// KnF: fragment-major K for GEMM1. elem offset of frag (chunk,kb,nhh,lane):
//   chunk*32768 + kb*2048 + nhh*512 + lane*8   (nhh = nh*2+half)
constexpr int CSTEP = 16 * 4 * 64 * 8;  // 32768 elems per 64-key chunk

typedef __attribute__((ext_vector_type(8))) short    short8;
typedef __attribute__((ext_vector_type(4))) float    floatx4;
typedef __attribute__((ext_vector_type(4))) uint32_t uint4v;
typedef __attribute__((ext_vector_type(2))) uint32_t uint2v;

__device__ inline uint32_t f2bf1(float f) {
  union { float f; uint32_t u; } v; v.f = f;
  return (v.u + 0x7FFFu + ((v.u >> 16) & 1u)) >> 16;   // RNE
}
__device__ inline uint32_t pack2(float a, float b) {
  return f2bf1(a) | (f2bf1(b) << 16);
}

// ---------------- normalize Q -> Qn (bf16), and init out = Q ----------------
__global__ void norm_q_kernel(const float* __restrict__ q,
                              float* __restrict__ out,
                              unsigned short* __restrict__ Qn) {
  const int wave = threadIdx.x >> 6, lane = threadIdx.x & 63;
  const int row = blockIdx.x * 4 + wave;
  const float4* qr = (const float4*)(q + (size_t)row * D);
  float4 a = qr[lane * 2];
  float4 b = qr[lane * 2 + 1];
  float ss = a.x*a.x + a.y*a.y + a.z*a.z + a.w*a.w
           + b.x*b.x + b.y*b.y + b.z*b.z + b.w*b.w;
#pragma unroll
  for (int m = 32; m >= 1; m >>= 1) ss += __shfl_xor(ss, m, 64);
  const float sc = 1.0f / fmaxf(sqrtf(ss), 1e-12f);
  float4* orow = (float4*)(out + (size_t)row * D);
  orow[lane * 2]     = a;
  orow[lane * 2 + 1] = b;
  uint4v w;
  w.x = pack2(a.x*sc, a.y*sc); w.y = pack2(a.z*sc, a.w*sc);
  w.z = pack2(b.x*sc, b.y*sc); w.w = pack2(b.z*sc, b.w*sc);
  *(uint4v*)(Qn + (size_t)row * D + lane * 8) = w;
}

// -- normalize K -> KnF (bf16, GEMM1-fragment-major) + KnT (bf16, transposed)
__global__ void norm_k_kernel(const float* __restrict__ k,
                              unsigned short* __restrict__ KnF,
                              unsigned short* __restrict__ KnT) {
  __shared__ unsigned short tile[64 * KROW];
  const int wave = threadIdx.x >> 6, lane = threadIdx.x & 63;
  const int l15 = lane & 15, quad = lane >> 4;
  const int n0 = blockIdx.x * 64;
#pragma unroll 1
  for (int i = 0; i < 16; ++i) {
    const int rl = wave * 16 + i;
    const int n  = n0 + rl;
    const float4* kr = (const float4*)(k + (size_t)n * D);
    float4 a = kr[lane * 2], b = kr[lane * 2 + 1];
    float ss = a.x*a.x + a.y*a.y + a.z*a.z + a.w*a.w
             + b.x*b.x + b.y*b.y + b.z*b.z + b.w*b.w;
#pragma unroll
    for (int m = 32; m >= 1; m >>= 1) ss += __shfl_xor(ss, m, 64);
    const float sc = 1.0f / fmaxf(sqrtf(ss), 1e-12f);
    uint4v w;
    w.x = pack2(a.x*sc, a.y*sc); w.y = pack2(a.z*sc, a.w*sc);
    w.z = pack2(b.x*sc, b.y*sc); w.w = pack2(b.z*sc, b.w*sc);
    *(uint4v*)&tile[rl * KROW + lane * 8] = w;
  }
  __syncthreads();
  // KnT: [d][n] for GEMM2 B-operands
  {
    const int dsub = threadIdx.x >> 3;        // 0..31
    const int nl   = (threadIdx.x & 7) * 8;   // 0..56
#pragma unroll 1
    for (int iter = 0; iter < 16; ++iter) {
      const int d = iter * 32 + dsub;
      uint4v w;
      w.x = (uint32_t)tile[(nl+0)*KROW + d] | ((uint32_t)tile[(nl+1)*KROW + d] << 16);
      w.y = (uint32_t)tile[(nl+2)*KROW + d] | ((uint32_t)tile[(nl+3)*KROW + d] << 16);
      w.z = (uint32_t)tile[(nl+4)*KROW + d] | ((uint32_t)tile[(nl+5)*KROW + d] << 16);
      w.w = (uint32_t)tile[(nl+6)*KROW + d] | ((uint32_t)tile[(nl+7)*KROW + d] << 16);
      *(uint4v*)(KnT + (size_t)d * NK + n0 + nl) = w;
    }
  }
  // KnF: fragment-major for GEMM1 A-operands. wave = nhh (rows nhh*16..+15)
  {
    const int nhh = wave;   // 0..3
    unsigned short* dst = KnF + (size_t)blockIdx.x * CSTEP + nhh * 512 + lane * 8;
#pragma unroll
    for (int kb = 0; kb < 16; ++kb) {
      uint4v v = *(const uint4v*)&tile[(nhh*16 + l15) * KROW + kb*32 + quad*8];
      *(uint4v*)(dst + kb * 2048) = v;
    }
  }
}

// ---------------- fused: S = Qn Kn^T chunk, P = exp, O += P Kn --------------
// NO K staging in LDS: GEMM1 A-frags stream from KnF (fragment-major,
// perfectly coalesced, L2-resident per XCD). LDS = P double-buffer only.
// One barrier per chunk. Epilogue: atomicAdd (proved L2-coalesced in R1).
__global__ __launch_bounds__(512, 2) void fused_kernel(
    const unsigned short* __restrict__ Qn,
    const unsigned short* __restrict__ KnF,
    const unsigned short* __restrict__ KnT,
    float* __restrict__ out) {
  __shared__ unsigned short P_lds[2][BQ * PROW];   // 2 x 9.2 KB = 18.4 KB

  const int tid  = threadIdx.x;
  const int wave = tid >> 6, lane = tid & 63;
  const int l15  = lane & 15, quad = lane >> 4;
  const int nsplit = blockIdx.x & (NSPLIT - 1);   // == XCD id under round-robin
  const int qtile  = blockIdx.x >> 3;             // 0..63
  const int q0     = qtile * BQ;
  const int nbase  = nsplit * NRANGE;
  const int cbase  = nsplit * CHUNKS;             // global chunk index base
  const int tb = wave & 3, nh = wave >> 2;

  // Q B-fragments in registers: wave's 16-col b-tile, all 512 d (64 VGPR)
  short8 qf[16];
  {
    const unsigned short* qrow = Qn + (size_t)(q0 + tb * 16 + l15) * D + quad * 8;
#pragma unroll
    for (int kb = 0; kb < 16; ++kb) qf[kb] = *(const short8*)(qrow + kb * 32);
  }

  floatx4 oacc[4][4] = {};   // wave's 64x64 O slice (cols wave*64..+63)
  short8 ktf[2][4];          // KnT B-fragments (32 VGPR), single-buffered
  short8 af[4][2];           // GEMM1 A-frag ring: 4 kb-steps x (a0,a1) (32 VGPR)

  // per-wave KnF base: + chunk*CSTEP + kb*2048 + half*512 gives the frag
  const unsigned short* pA0 = KnF + (size_t)cbase * CSTEP + nh * 1024 + lane * 8;

  // prologue: ktf(chunk 0), af ring (chunk 0, kb 0..3)
#pragma unroll
  for (int kb2 = 0; kb2 < 2; ++kb2)
#pragma unroll
    for (int td = 0; td < 4; ++td)
      ktf[kb2][td] = *(const short8*)(KnT + (size_t)(wave*64 + td*16 + l15) * NK
                                      + (nbase + kb2*32 + quad*8));
#pragma unroll
  for (int g = 0; g < 4; ++g) {
    af[g][0] = *(const short8*)(pA0 + g * 2048);
    af[g][1] = *(const short8*)(pA0 + g * 2048 + 512);
  }

#pragma unroll 1
  for (int c = 0; c < CHUNKS; ++c) {
    const int cur = c & 1;
    const int cn = (c + 1 < CHUNKS) ? c + 1 : c;   // clamp (harmless reload)
    const unsigned short* pAc = pA0 + (size_t)c  * CSTEP;
    const unsigned short* pAn = pA0 + (size_t)cn * CSTEP;

    // ---- GEMM1: A streamed from KnF via 4-deep ring, B = qf (regs)
    floatx4 s0 = {}, s1 = {};
#pragma unroll
    for (int kb = 0; kb < 16; ++kb) {
      short8 a0 = af[kb & 3][0], a1 = af[kb & 3][1];
      const int pk = kb + 4;
      const unsigned short* fp = (pk < 16) ? (pAc + pk * 2048)
                                           : (pAn + (pk - 16) * 2048);
      af[kb & 3][0] = *(const short8*)(fp);
      af[kb & 3][1] = *(const short8*)(fp + 512);
      s0 = __builtin_amdgcn_mfma_f32_16x16x32_bf16(a0, qf[kb], s0, 0, 0, 0);
      s1 = __builtin_amdgcn_mfma_f32_16x16x32_bf16(a1, qf[kb], s1, 0, 0, 0);
    }

    // ---- exp + pack to bf16, one 8B LDS write per tile
    {
      const int prow = (tb * 16 + l15) * PROW;
      uint2v w0, w1;
      w0.x = pack2(__expf(BETA * (s0[0] - 1.f)), __expf(BETA * (s0[1] - 1.f)));
      w0.y = pack2(__expf(BETA * (s0[2] - 1.f)), __expf(BETA * (s0[3] - 1.f)));
      w1.x = pack2(__expf(BETA * (s1[0] - 1.f)), __expf(BETA * (s1[1] - 1.f)));
      w1.y = pack2(__expf(BETA * (s1[2] - 1.f)), __expf(BETA * (s1[3] - 1.f)));
      *(uint2v*)&P_lds[cur][prow + (nh*2 + 0) * 16 + quad * 4] = w0;
      *(uint2v*)&P_lds[cur][prow + (nh*2 + 1) * 16 + quad * 4] = w1;
    }

    // ---- the ONLY barrier: P(c) visible to all waves
    __syncthreads();

    // ---- GEMM2: O += P (LDS, A-op) * KnT (regs, B-op)
#pragma unroll
    for (int kb2 = 0; kb2 < 2; ++kb2) {
      short8 pf[4];
#pragma unroll
      for (int tr = 0; tr < 4; ++tr)
        pf[tr] = *(const short8*)&P_lds[cur][(tr*16 + l15) * PROW + kb2*32 + quad*8];
#pragma unroll
      for (int td = 0; td < 4; ++td)
#pragma unroll
        for (int tr = 0; tr < 4; ++tr)
          oacc[tr][td] = __builtin_amdgcn_mfma_f32_16x16x32_bf16(
              pf[tr], ktf[kb2][td], oacc[tr][td], 0, 0, 0);
    }

    // ---- load next chunk's KnT frags (drained by barrier(c+1), ~GEMM1 away)
#pragma unroll
    for (int kb2 = 0; kb2 < 2; ++kb2)
#pragma unroll
      for (int td = 0; td < 4; ++td)
        ktf[kb2][td] = *(const short8*)(KnT + (size_t)(wave*64 + td*16 + l15) * NK
                                        + (nbase + cn*BN + kb2*32 + quad*8));
  }

  // ---- epilogue: out += ALPHA * O (out pre-initialized to Q by norm_q;
  //      atomics coalesce in L2 — measured 33MB WRITE in R1, not write-through)
  const int colbase = wave * 64 + l15;
#pragma unroll
  for (int tr = 0; tr < 4; ++tr)
#pragma unroll
    for (int td = 0; td < 4; ++td)
#pragma unroll
      for (int r = 0; r < 4; ++r)
        atomicAdd(out + (size_t)(q0 + tr*16 + quad*4 + r) * D + colbase + td*16,
                  ALPHA * oacc[tr][td][r]);
}

extern "C" void kernel_launch(void* const* d_in, const int* in_sizes, int n_in,
                              void* d_out, int out_size, void* d_ws, size_t ws_size,
                              hipStream_t stream) {
  (void)in_sizes; (void)n_in; (void)out_size; (void)ws_size;
  const float* q = (const float*)d_in[0];
  const float* k = (const float*)d_in[1];
  float* out = (float*)d_out;
  unsigned short* Qn  = (unsigned short*)d_ws;          //  4 MB
  unsigned short* KnF = Qn + (size_t)NB * D;            // 16 MB
  unsigned short* KnT = KnF + (size_t)NK * D;           // 16 MB  (total 36 MB)

  hipLaunchKernelGGL(norm_q_kernel, dim3(NB / 4),  dim3(256), 0, stream, q, out, Qn);
  hipLaunchKernelGGL(norm_k_kernel, dim3(NK / 64), dim3(256), 0, stream, k, KnF, KnT);
  hipLaunchKernelGGL(fused_kernel, dim3((NB / BQ) * NSPLIT), dim3(512), 0, stream,
                     Qn, KnF, KnT, out);
}

// Round 7
// 352.134 us; speedup vs baseline: 1.1276x; 1.1276x over previous
//
#include <hip/hip_runtime.h>
#include <cstdint>
#include <cstddef>

#define BETA 5.5f
#define ALPHA 0.5f

constexpr int D   = 512;     // feature dim
constexpr int NB  = 4096;    // queries
constexpr int NK  = 16384;   // keys
constexpr int BQ  = 64;      // query tile per block
constexpr int BN  = 64;      // key chunk
constexpr int NSPLIT = 4;
constexpr int NRANGE = NK / NSPLIT;   // 4096
constexpr int CHUNKS = NRANGE / BN;   // 64
constexpr int KROW = D + 8;           // padded LDS row (bf16): 520 elems, 1040 B (16B-mult)
constexpr int PROW = BN + 8;          // padded P row: 72

typedef __attribute__((ext_vector_type(8)))  short    short8;
typedef __attribute__((ext_vector_type(4)))  float    floatx4;
typedef __attribute__((ext_vector_type(16))) float    floatx16;
typedef __attribute__((ext_vector_type(4)))  uint32_t uint4v;
typedef __attribute__((ext_vector_type(2)))  uint32_t uint2v;

__device__ inline uint32_t f2bf1(float f) {
  union { float f; uint32_t u; } v; v.f = f;
  return (v.u + 0x7FFFu + ((v.u >> 16) & 1u)) >> 16;   // RNE
}
__device__ inline uint32_t pack2(float a, float b) {
  return f2bf1(a) | (f2bf1(b) << 16);
}

__device__ inline void load_lds16(const void* g, void* l) {
  __builtin_amdgcn_global_load_lds(
      (const __attribute__((address_space(1))) uint32_t*)g,
      (__attribute__((address_space(3))) uint32_t*)l, 16, 0, 0);
}

// ---------------- normalize Q -> Qn (bf16), and init out = Q ----------------
__global__ void norm_q_kernel(const float* __restrict__ q,
                              float* __restrict__ out,
                              unsigned short* __restrict__ Qn) {
  const int wave = threadIdx.x >> 6, lane = threadIdx.x & 63;
  const int row = blockIdx.x * 4 + wave;
  const float4* qr = (const float4*)(q + (size_t)row * D);
  float4 a = qr[lane * 2];
  float4 b = qr[lane * 2 + 1];
  float ss = a.x*a.x + a.y*a.y + a.z*a.z + a.w*a.w
           + b.x*b.x + b.y*b.y + b.z*b.z + b.w*b.w;
#pragma unroll
  for (int m = 32; m >= 1; m >>= 1) ss += __shfl_xor(ss, m, 64);
  const float sc = 1.0f / fmaxf(sqrtf(ss), 1e-12f);
  float4* orow = (float4*)(out + (size_t)row * D);
  orow[lane * 2]     = a;
  orow[lane * 2 + 1] = b;
  uint4v w;
  w.x = pack2(a.x*sc, a.y*sc); w.y = pack2(a.z*sc, a.w*sc);
  w.z = pack2(b.x*sc, b.y*sc); w.w = pack2(b.z*sc, b.w*sc);
  *(uint4v*)(Qn + (size_t)row * D + lane * 8) = w;
}

// ------ normalize K -> Kn (bf16 row-major) + KnT (bf16 transposed) ----------
// 1024 threads (16 waves): norm loop 4 rows/wave, transpose 4 iters.
__global__ void norm_k_kernel(const float* __restrict__ k,
                              unsigned short* __restrict__ Kn,
                              unsigned short* __restrict__ KnT) {
  __shared__ unsigned short tile[64 * KROW];
  const int wave = threadIdx.x >> 6, lane = threadIdx.x & 63;
  const int n0 = blockIdx.x * 64;
#pragma unroll
  for (int i = 0; i < 4; ++i) {
    const int rl = wave * 4 + i;
    const int n  = n0 + rl;
    const float4* kr = (const float4*)(k + (size_t)n * D);
    float4 a = kr[lane * 2], b = kr[lane * 2 + 1];
    float ss = a.x*a.x + a.y*a.y + a.z*a.z + a.w*a.w
             + b.x*b.x + b.y*b.y + b.z*b.z + b.w*b.w;
#pragma unroll
    for (int m = 32; m >= 1; m >>= 1) ss += __shfl_xor(ss, m, 64);
    const float sc = 1.0f / fmaxf(sqrtf(ss), 1e-12f);
    uint4v w;
    w.x = pack2(a.x*sc, a.y*sc); w.y = pack2(a.z*sc, a.w*sc);
    w.z = pack2(b.x*sc, b.y*sc); w.w = pack2(b.z*sc, b.w*sc);
    *(uint4v*)(Kn + (size_t)n * D + lane * 8) = w;
    *(uint4v*)&tile[rl * KROW + lane * 8]     = w;
  }
  __syncthreads();
  const int dsub = threadIdx.x >> 3;        // 0..127
  const int nl   = (threadIdx.x & 7) * 8;   // 0..56
#pragma unroll
  for (int iter = 0; iter < 4; ++iter) {
    const int d = iter * 128 + dsub;
    uint4v w;
    w.x = (uint32_t)tile[(nl+0)*KROW + d] | ((uint32_t)tile[(nl+1)*KROW + d] << 16);
    w.y = (uint32_t)tile[(nl+2)*KROW + d] | ((uint32_t)tile[(nl+3)*KROW + d] << 16);
    w.z = (uint32_t)tile[(nl+4)*KROW + d] | ((uint32_t)tile[(nl+5)*KROW + d] << 16);
    w.w = (uint32_t)tile[(nl+6)*KROW + d] | ((uint32_t)tile[(nl+7)*KROW + d] << 16);
    *(uint4v*)(KnT + (size_t)d * NK + n0 + nl) = w;
  }
}

// ---------------- fused: S = Qn Kn^T chunk, P = exp, O += P Kn --------------
// GEMM1: 32x32x16 MFMA, k-split across wave pairs -> A-frags read 2x (not 4x)
// from LDS. kh-halves reduced via 16KB LDS buffer. GEMM2: 16x16x32, as R5.
// K_lds double-buffered via global_load_lds; 2 barriers/chunk; atomic epilogue.
__global__ __launch_bounds__(512, 2) void fused_kernel(
    const unsigned short* __restrict__ Qn,
    const unsigned short* __restrict__ Kn,
    const unsigned short* __restrict__ KnT,
    float* __restrict__ out) {
  __shared__ unsigned short K_lds[2][BN * KROW];   // 133120 B
  __shared__ unsigned short P_lds[BQ * PROW];      //   9216 B (single buffer)
  __shared__ float Sred[4][32 * 32];               //  16384 B   total 158.7 KB

  const int tid  = threadIdx.x;
  const int wave = tid >> 6, lane = tid & 63;
  const int l15  = lane & 15, quad = lane >> 4;
  const int l31  = lane & 31, half = lane >> 5;
  const int nsplit = blockIdx.x & (NSPLIT - 1);
  const int qtile  = blockIdx.x >> 2;           // 0..63
  const int q0     = qtile * BQ;
  const int nbase  = nsplit * NRANGE;
  // GEMM1 roles: tile (nt2, qt2) of S^T, k-half kh
  const int nt2 = wave & 1, qt2 = (wave >> 1) & 1, kh = wave >> 2;
  const int g1tile = nt2 * 2 + qt2;

  // GEMM1 B-frags (Q): B[k=16][n=32], n=l31, k=half*8+j. 16 steps = 64 VGPR.
  short8 qfB[16];
  {
    const unsigned short* qrow = Qn + (size_t)(q0 + qt2*32 + l31) * D
                                 + kh * 256 + half * 8;
#pragma unroll
    for (int ks = 0; ks < 16; ++ks) qfB[ks] = *(const short8*)(qrow + ks * 16);
  }

  floatx4 oacc[4][4] = {};   // wave's 64q x 64d O slice (cols wave*64..+63)
  short8 ktf[2][4];          // KnT B-frags for GEMM2 (32 VGPR), single-buffered

  // prologue: stage chunk 0, load chunk-0 ktf
#pragma unroll
  for (int i = 0; i < 8; ++i) {
    const int row = wave * 8 + i;
    load_lds16(Kn + (size_t)(nbase + row) * D + lane * 8, &K_lds[0][row * KROW]);
  }
#pragma unroll
  for (int kb2 = 0; kb2 < 2; ++kb2)
#pragma unroll
    for (int td = 0; td < 4; ++td)
      ktf[kb2][td] = *(const short8*)(KnT + (size_t)(wave*64 + td*16 + l15) * NK
                                      + (nbase + kb2*32 + quad*8));
  __syncthreads();   // chunk-0 staging visible

#pragma unroll 1
  for (int c = 0; c < CHUNKS; ++c) {
    const int cur = c & 1, nxt = cur ^ 1;
    const int cn = (c + 1 < CHUNKS) ? c + 1 : c;

    // ---- issue next chunk's staging (drained by barrier A, ~GEMM1 away)
    if (c + 1 < CHUNKS) {
#pragma unroll
      for (int i = 0; i < 8; ++i) {
        const int row = wave * 8 + i;
        load_lds16(Kn + (size_t)(nbase + (c+1)*BN + row) * D + lane * 8,
                   &K_lds[nxt][row * KROW]);
      }
    }

    // ---- GEMM1: one 32x32 S^T tile per wave-pair, half-D per wave.
    //      A[m=l31 key-row][k=half*8+j] from K_lds, B = qfB regs.
    floatx16 s = {};
    {
      const unsigned short* abase =
          &K_lds[cur][(nt2*32 + l31) * KROW + kh * 256 + half * 8];
#pragma unroll
      for (int ks = 0; ks < 16; ++ks) {
        short8 a = *(const short8*)(abase + ks * 16);
        s = __builtin_amdgcn_mfma_f32_32x32x16_bf16(a, qfB[ks], s, 0, 0, 0);
      }
    }

    // ---- kh=1 waves export partial S (lane-symmetric layout: trivially safe)
    if (kh == 1) {
      float* sr = &Sred[g1tile][lane * 16];
#pragma unroll
      for (int g = 0; g < 4; ++g) {
        float4 v = { s[4*g], s[4*g+1], s[4*g+2], s[4*g+3] };
        ((float4*)sr)[g] = v;
      }
    }
    __syncthreads();   // barrier A: Sred visible; staging(c+1) drained

    // ---- kh=0 waves: reduce halves, exp, pack, write P (GEMM2-A layout)
    if (kh == 0) {
      const float* sr = &Sred[g1tile][lane * 16];
      const int q = qt2 * 32 + l31;
#pragma unroll
      for (int g = 0; g < 4; ++g) {
        float4 r = ((const float4*)sr)[g];
        float e0 = __expf(BETA * (s[4*g+0] + r.x - 1.f));
        float e1 = __expf(BETA * (s[4*g+1] + r.y - 1.f));
        float e2 = __expf(BETA * (s[4*g+2] + r.z - 1.f));
        float e3 = __expf(BETA * (s[4*g+3] + r.w - 1.f));
        // C/D rows (keys) for regs 4g..4g+3: nt2*32 + 8g + 4*half + {0..3}
        uint2v w; w.x = pack2(e0, e1); w.y = pack2(e2, e3);
        *(uint2v*)&P_lds[q * PROW + nt2*32 + g*8 + half*4] = w;
      }
    }
    __syncthreads();   // barrier B: P(c) visible

    // ---- GEMM2: O += P (LDS, A-op) * KnT (regs, B-op)   [16x16x32, as R5]
#pragma unroll
    for (int kb2 = 0; kb2 < 2; ++kb2) {
      short8 pf[4];
#pragma unroll
      for (int tr = 0; tr < 4; ++tr)
        pf[tr] = *(const short8*)&P_lds[(tr*16 + l15) * PROW + kb2*32 + quad*8];
#pragma unroll
      for (int td = 0; td < 4; ++td)
#pragma unroll
        for (int tr = 0; tr < 4; ++tr)
          oacc[tr][td] = __builtin_amdgcn_mfma_f32_16x16x32_bf16(
              pf[tr], ktf[kb2][td], oacc[tr][td], 0, 0, 0);
    }

    // ---- prefetch next chunk's ktf (drained by barrier A of c+1)
#pragma unroll
    for (int kb2 = 0; kb2 < 2; ++kb2)
#pragma unroll
      for (int td = 0; td < 4; ++td)
        ktf[kb2][td] = *(const short8*)(KnT + (size_t)(wave*64 + td*16 + l15) * NK
                                        + (nbase + cn*BN + kb2*32 + quad*8));
  }

  // ---- epilogue: out += ALPHA * O (out pre-init to Q; atomics L2-coalesce)
  const int colbase = wave * 64 + l15;
#pragma unroll
  for (int tr = 0; tr < 4; ++tr)
#pragma unroll
    for (int td = 0; td < 4; ++td)
#pragma unroll
      for (int r = 0; r < 4; ++r)
        atomicAdd(out + (size_t)(q0 + tr*16 + quad*4 + r) * D + colbase + td*16,
                  ALPHA * oacc[tr][td][r]);
}

extern "C" void kernel_launch(void* const* d_in, const int* in_sizes, int n_in,
                              void* d_out, int out_size, void* d_ws, size_t ws_size,
                              hipStream_t stream) {
  (void)in_sizes; (void)n_in; (void)out_size; (void)ws_size;
  const float* q = (const float*)d_in[0];
  const float* k = (const float*)d_in[1];
  float* out = (float*)d_out;
  unsigned short* Qn  = (unsigned short*)d_ws;          //  4 MB
  unsigned short* Kn  = Qn + (size_t)NB * D;            // 16 MB
  unsigned short* KnT = Kn + (size_t)NK * D;            // 16 MB  (total 36 MB)

  hipLaunchKernelGGL(norm_q_kernel, dim3(NB / 4),  dim3(256),  0, stream, q, out, Qn);
  hipLaunchKernelGGL(norm_k_kernel, dim3(NK / 64), dim3(1024), 0, stream, k, Kn, KnT);
  hipLaunchKernelGGL(fused_kernel, dim3((NB / BQ) * NSPLIT), dim3(512), 0, stream,
                     Qn, Kn, KnT, out);
}